// Round 9
// baseline (694.590 us; speedup 1.0000x reference)
//
#include <hip/hip_runtime.h>

#define CCH   640
#define RDIM  128
#define HWPIX 100
#define NBS   25
#define NBQ   75
#define CKK   5760
#define SF_B  64000

// ---------------- Workspace layout (float offsets) ----------------
#define OFF_PG0   0        // [25][640] pooled, b-major
#define OFF_PGA   16000
#define OFF_PGB   32000
#define OFF_ATA   48000    // [640][9]
#define OFF_ATB   53760
#define OFF_BA    59520    // [16]
#define OFF_BB    59536
#define OFF_HP    59552    // [50][4][128] mlp1 partials
#define OFF_SKT   85152    // [2][25][900]  uv-major view layout: [b][uv*100+p]
#define OFF_SKS   130152   // [2][25][900]  same layout
#define OFF_SKSCT 175152   // [9][25][100]  combined instance sk, uv-major
#define OFF_CKS   316052   // [25][5760]
#define OFF_TASKT 485652   // [9][640][100] task kernel transposed

// pooled(sf) -> [b][c] layout  (verbatim R0)
__global__ void pool_kernel(const float* __restrict__ sf, float* __restrict__ Pg0) {
    int idx = blockIdx.x * 64 + threadIdx.x;
    if (idx >= NBS * CCH) return;
    int b = idx / CCH, c = idx % CCH;
    const float4* s4 = (const float4*)(sf + b * SF_B + c * HWPIX);
    float acc = 0.f;
#pragma unroll
    for (int q = 0; q < 25; ++q) {
        float4 v = s4[q];
        acc += (v.x + v.y) + (v.z + v.w);
    }
    Pg0[idx] = acc * 0.01f;
}

// One chain stage (verbatim R0).
__global__ void chain_step(const float* __restrict__ Pin, const float* __restrict__ Wp,
                           const float* __restrict__ bp, float* __restrict__ Pout,
                           const float* __restrict__ Ain, const float* __restrict__ Wa,
                           const float* __restrict__ ba, const float* __restrict__ Bin,
                           float* __restrict__ Aout, float* __restrict__ Bout,
                           int first, const float* __restrict__ Ws, const float* __restrict__ bs) {
    __shared__ float red[256];
    int blk = blockIdx.x, t = threadIdx.x;
    int lane = t & 63;
    if (blk < 4000) {
        int W = blk * 4 + (t >> 6);          // 0..15999
        int o = W / NBS, b = W % NBS;
        const float2* w2 = (const float2*)(Wp + o * CCH);
        const float2* p2 = (const float2*)(Pin + b * CCH);
        float acc = 0.f;
#pragma unroll
        for (int s = 0; s < 5; ++s) {
            float2 wv = w2[s * 64 + lane];
            float2 pv = p2[s * 64 + lane];
            acc += wv.x * pv.x + wv.y * pv.y;
        }
#pragma unroll
        for (int m = 32; m >= 1; m >>= 1) acc += __shfl_xor(acc, m);
        if (lane == 0) Pout[b * CCH + o] = acc + bp[o];
    } else if (blk < 4090) {
        int w = blk - 4000;                  // 0..89
        int k = w / 10, ctile = w % 10;
        int og = t >> 6, cl = lane;
        int c = ctile * 64 + cl;
        int o0 = og * 160;
        float acc = 0.f;
        if (first) {
            const float* ar = Ws + k * CCH;
#pragma unroll 8
            for (int o = o0; o < o0 + 160; ++o)
                acc += ar[o] * Wa[o * CCH + c];
        } else {
#pragma unroll 8
            for (int o = o0; o < o0 + 160; ++o)
                acc += Ain[o * 9 + k] * Wa[o * CCH + c];
        }
        red[t] = acc;
        __syncthreads();
        if (t < 64) {
            float s = red[t] + red[64 + t] + red[128 + t] + red[192 + t];
            Aout[(ctile * 64 + t) * 9 + k] = s;
        }
    } else {
        int WB = (blk - 4090) * 4 + (t >> 6);
        if (WB >= 9) return;
        int k = WB;
        float acc = 0.f;
        if (first) {
            const float* ar = Ws + k * CCH;
#pragma unroll
            for (int s = 0; s < 10; ++s) acc += ar[s * 64 + lane] * ba[s * 64 + lane];
        } else {
#pragma unroll
            for (int s = 0; s < 10; ++s) acc += Ain[(s * 64 + lane) * 9 + k] * ba[s * 64 + lane];
        }
#pragma unroll
        for (int m = 32; m >= 1; m >>= 1) acc += __shfl_xor(acc, m);
        if (lane == 0) Bout[k] = acc + (first ? bs[k] : Bin[k]);
    }
}

// mlp1 K-split partials + fused sk (verbatim R0).
__global__ void postchain(const float* __restrict__ sf, const float* __restrict__ Pg0,
                          const float* __restrict__ Pgf, const float* __restrict__ W1,
                          float* __restrict__ Hp, const float* __restrict__ A4T,
                          const float* __restrict__ betaF, const float* __restrict__ Ws,
                          const float* __restrict__ bs, float* __restrict__ SKT,
                          float* __restrict__ SKS) {
    int blk = blockIdx.x, t = threadIdx.x;
    if (blk < 100) {
        int pair = blk / 2;
        int s = (blk % 2) * 2 + (t >> 7);
        int r = t & 127;
        int branch = pair / NBS, b = pair % NBS;
        const float* prow = (branch ? Pg0 : Pgf) + b * CCH;
        int c0 = s * 160;
        float acc = 0.f;
#pragma unroll 8
        for (int c = 0; c < 160; ++c)
            acc += prow[c0 + c] * W1[(c0 + c) * RDIM + r];
        Hp[(pair * 4 + s) * RDIM + r] = acc;
    } else {
        int sidx = (blk - 100) * 256 + t;
        if (sidx >= 45000) return;
        int s = sidx / 22500;
        int rem = sidx % 22500;
        int b = rem / 900;
        int r2 = rem % 900;          // flat f = k*100 + q
        int k = r2 / HWPIX, q = r2 % HWPIX;
        const float* x = sf + b * SF_B + q;
        const float* wsr = Ws + k * CCH;
        int c0 = s * 320;
        float acc0 = 0.f, acc1 = 0.f;
#pragma unroll 8
        for (int c = 0; c < 320; ++c) {
            float xc = x[(c0 + c) * HWPIX];
            acc0 += A4T[(c0 + c) * 9 + k] * xc;
            acc1 += wsr[c0 + c] * xc;
        }
        if (s == 0) { acc0 += betaF[k]; acc1 += bs[k]; }
        int p = r2 / 9, uv = r2 % 9;           // view coords of flat offset r2
        int dst = s * 22500 + b * 900 + uv * 100 + p;
        SKT[dst] = acc0;
        SKS[dst] = acc1;
    }
}

// Fused: h finalize + ck (both branches) + task assemble + sksT combine.
// Replaces mlp_phase2 + task_assemble. Task-branch ck lives only in LDS.
// blk 0..19: c-chunk of 32 (j-range 288). blk 20..107: sksT combine.
__global__ __launch_bounds__(256) void ck_task(
        const float* __restrict__ Hp, const float* __restrict__ b1,
        const float* __restrict__ W2, const float* __restrict__ b2,
        const float* __restrict__ SKT, const float* __restrict__ SKS,
        float* __restrict__ CKS, float* __restrict__ TKT,
        float* __restrict__ sksT) {
    int blk = blockIdx.x, t = threadIdx.x;
    if (blk < 20) {
        __shared__ float h[50 * RDIM];        // 25.6 KB
        __shared__ float ckt_l[25 * 288];     // 28.8 KB  (total 54.4 KB)
        int c0 = blk * 32;
        int j0 = c0 * 9;
        // Stage1: finalize h for all 50 (branch,b) pairs. 6400 = 25*256.
        for (int o = t; o < 50 * RDIM; o += 256) {
            int pair = o >> 7, r = o & 127;
            const float* hp = Hp + pair * 4 * RDIM;
            float v = b1[r] + hp[r] + hp[RDIM + r] + hp[2 * RDIM + r] + hp[3 * RDIM + r];
            h[o] = fmaxf(v, 0.f);
        }
        __syncthreads();
        // Stage2: ck for j-range, all 50 pairs. pair<25 -> LDS (task), else CKS.
        for (int o = t; o < 50 * 288; o += 256) {
            int pair = o / 288, jj = o % 288;
            int j = j0 + jj;
            const float* hrow = h + pair * RDIM;
            float acc = b2[j];
#pragma unroll 4
            for (int r = 0; r < RDIM; ++r)
                acc += hrow[r] * W2[r * CKK + j];
            if (pair < 25) ckt_l[pair * 288 + jj] = acc;
            else           CKS[(pair - 25) * CKK + j] = acc;
        }
        __syncthreads();
        // Stage3: task assemble for this c-chunk. 28800 outputs.
        for (int o = t; o < 28800; o += 256) {
            int uv = o / 3200;
            int rem = o % 3200;
            int cl = rem / 100, p = rem % 100;
            float acc = 0.f;
#pragma unroll
            for (int b = 0; b < NBS; ++b)
                acc += ckt_l[b * 288 + cl * 9 + uv] *
                       (SKT[b * 900 + uv * 100 + p] + SKT[22500 + b * 900 + uv * 100 + p]);
            TKT[uv * 64000 + (c0 + cl) * 100 + p] = acc * 0.04f;
        }
    } else {
        int cidx = (blk - 20) * 256 + t;
        if (cidx < 22500) {
            int uv = cidx / 2500;
            int r = cidx % 2500;              // b*100+p
            int src = (r / 100) * 900 + uv * 100 + (r % 100);
            sksT[cidx] = SKS[src] + SKS[22500 + src];
        }
    }
}

// Involutions, image-loop restructure: block owns 256 (c,p) pairs x 25 images;
// taskT read once into registers (was ~100x re-read = ~230 MB of L2 traffic).
// g=0 blocks are all-support, g=1..3 all-query -> branch is block-uniform.
__global__ __launch_bounds__(256) void involutions(
        const float* __restrict__ sf, const float* __restrict__ qf,
        const float* __restrict__ taskT, const float* __restrict__ cks,
        const float* __restrict__ sksT, float* __restrict__ out) {
    int blk = blockIdx.x, t = threadIdx.x;
    int g = blk / 250;                         // image group: 25 images each
    int cpidx = (blk % 250) * 256 + t;         // 0..63999 exactly
    int c = cpidx / 100, p = cpidx % 100;
    int i = p / 10, j = p % 10;

    float tk[9];
#pragma unroll
    for (int uv = 0; uv < 9; ++uv) tk[uv] = taskT[uv * 64000 + cpidx];

    int im0 = g * 25;
#pragma unroll 1
    for (int im = im0; im < im0 + 25; ++im) {
        bool support = im < NBS;               // uniform within block
        const float* x = (support ? sf + im * SF_B : qf + (im - NBS) * SF_B) + c * 100;
        float w[9];
        if (support) {
#pragma unroll
            for (int uv = 0; uv < 9; ++uv)
                w[uv] = tk[uv] * cks[im * CKK + c * 9 + uv] *
                        sksT[uv * 2500 + im * 100 + p];
        } else {
#pragma unroll
            for (int uv = 0; uv < 9; ++uv) w[uv] = tk[uv];
        }
        float acc = 0.f;
#pragma unroll
        for (int u = 0; u < 3; ++u) {
            int ii = i + u - 1;
            float mrow = ((unsigned)ii < 10u) ? 1.f : 0.f;
            int ci = min(max(ii, 0), 9);
#pragma unroll
            for (int v = 0; v < 3; ++v) {
                int jj = j + v - 1;
                float m = ((unsigned)jj < 10u) ? mrow : 0.f;
                int cj = min(max(jj, 0), 9);
                float xv = x[ci * 10 + cj] * m;   // clamped addr, masked value
                acc += w[u * 3 + v] * xv;
            }
        }
        out[im * SF_B + cpidx] = acc;
    }
}

extern "C" void kernel_launch(void* const* d_in, const int* in_sizes, int n_in,
                              void* d_out, int out_size, void* d_ws, size_t ws_size,
                              hipStream_t stream) {
    const float* sf  = (const float*)d_in[0];
    const float* qf  = (const float*)d_in[1];
    const float* Wc[4] = {(const float*)d_in[2], (const float*)d_in[4],
                          (const float*)d_in[6], (const float*)d_in[8]};
    const float* bc[4] = {(const float*)d_in[3], (const float*)d_in[5],
                          (const float*)d_in[7], (const float*)d_in[9]};
    const float* W1 = (const float*)d_in[10];
    const float* b1 = (const float*)d_in[11];
    const float* W2 = (const float*)d_in[12];
    const float* b2 = (const float*)d_in[13];
    const float* Ws = (const float*)d_in[14];
    const float* bs = (const float*)d_in[15];
    float* out = (float*)d_out;
    float* ws = (float*)d_ws;

    float* Pg0 = ws + OFF_PG0;
    float* Pga = ws + OFF_PGA;
    float* Pgb = ws + OFF_PGB;
    float* ATa = ws + OFF_ATA;
    float* ATb = ws + OFF_ATB;
    float* Ba  = ws + OFF_BA;
    float* Bb  = ws + OFF_BB;
    float* Hp  = ws + OFF_HP;
    float* SKT = ws + OFF_SKT;
    float* SKS = ws + OFF_SKS;
    float* SKsT= ws + OFF_SKSCT;
    float* CKS = ws + OFF_CKS;
    float* TKT = ws + OFF_TASKT;

    pool_kernel<<<250, 64, 0, stream>>>(sf, Pg0);

    chain_step<<<4093, 256, 0, stream>>>(Pg0, Wc[0], bc[0], Pga, nullptr, Wc[3], bc[3], nullptr,
                                         ATa, Ba, 1, Ws, bs);
    chain_step<<<4093, 256, 0, stream>>>(Pga, Wc[1], bc[1], Pgb, ATa, Wc[2], bc[2], Ba,
                                         ATb, Bb, 0, Ws, bs);
    chain_step<<<4093, 256, 0, stream>>>(Pgb, Wc[2], bc[2], Pga, ATb, Wc[1], bc[1], Bb,
                                         ATa, Ba, 0, Ws, bs);
    chain_step<<<4093, 256, 0, stream>>>(Pga, Wc[3], bc[3], Pgb, ATa, Wc[0], bc[0], Ba,
                                         ATb, Bb, 0, Ws, bs);
    // pooled_t = Pgb, A4^T = ATb, beta4 = Bb

    postchain<<<276, 256, 0, stream>>>(sf, Pg0, Pgb, W1, Hp, ATb, Bb, Ws, bs, SKT, SKS);
    ck_task<<<108, 256, 0, stream>>>(Hp, b1, W2, b2, SKT, SKS, CKS, TKT, SKsT);
    involutions<<<1000, 256, 0, stream>>>(sf, qf, TKT, CKS, SKsT, out);
}

// Round 10
// 239.204 us; speedup vs baseline: 2.9038x; 2.9038x over previous
//
#include <hip/hip_runtime.h>

#define CCH   640
#define RDIM  128
#define HWPIX 100
#define NBS   25
#define NBQ   75
#define CKK   5760
#define SF_B  64000

// ---------------- Workspace layout (float offsets) ----------------
#define OFF_PG0   0        // [25][640] pooled, b-major
#define OFF_PGA   16000
#define OFF_PGB   32000
#define OFF_ATA   48000    // [640][9]
#define OFF_ATB   53760
#define OFF_BA    59520    // [16]
#define OFF_BB    59536
#define OFF_HP    59552    // [50][4][128] mlp1 partials
#define OFF_SKT   85152    // [2][25][900]  uv-major view layout: [b][uv*100+p]
#define OFF_SKS   130152   // [2][25][900]  same layout
#define OFF_SKSCT 175152   // [9][25][100]  combined instance sk, uv-major
#define OFF_CKT   197652   // [25][5760]
#define OFF_CKS   341652   // [25][5760]
#define OFF_TASKT 485652   // [9][640][100] task kernel transposed

// pooled(sf) -> [b][c] layout  (verbatim R0)
__global__ void pool_kernel(const float* __restrict__ sf, float* __restrict__ Pg0) {
    int idx = blockIdx.x * 64 + threadIdx.x;
    if (idx >= NBS * CCH) return;
    int b = idx / CCH, c = idx % CCH;
    const float4* s4 = (const float4*)(sf + b * SF_B + c * HWPIX);
    float acc = 0.f;
#pragma unroll
    for (int q = 0; q < 25; ++q) {
        float4 v = s4[q];
        acc += (v.x + v.y) + (v.z + v.w);
    }
    Pg0[idx] = acc * 0.01f;
}

// One chain stage (verbatim R0).
__global__ void chain_step(const float* __restrict__ Pin, const float* __restrict__ Wp,
                           const float* __restrict__ bp, float* __restrict__ Pout,
                           const float* __restrict__ Ain, const float* __restrict__ Wa,
                           const float* __restrict__ ba, const float* __restrict__ Bin,
                           float* __restrict__ Aout, float* __restrict__ Bout,
                           int first, const float* __restrict__ Ws, const float* __restrict__ bs) {
    __shared__ float red[256];
    int blk = blockIdx.x, t = threadIdx.x;
    int lane = t & 63;
    if (blk < 4000) {
        int W = blk * 4 + (t >> 6);          // 0..15999
        int o = W / NBS, b = W % NBS;
        const float2* w2 = (const float2*)(Wp + o * CCH);
        const float2* p2 = (const float2*)(Pin + b * CCH);
        float acc = 0.f;
#pragma unroll
        for (int s = 0; s < 5; ++s) {
            float2 wv = w2[s * 64 + lane];
            float2 pv = p2[s * 64 + lane];
            acc += wv.x * pv.x + wv.y * pv.y;
        }
#pragma unroll
        for (int m = 32; m >= 1; m >>= 1) acc += __shfl_xor(acc, m);
        if (lane == 0) Pout[b * CCH + o] = acc + bp[o];
    } else if (blk < 4090) {
        int w = blk - 4000;                  // 0..89
        int k = w / 10, ctile = w % 10;
        int og = t >> 6, cl = lane;
        int c = ctile * 64 + cl;
        int o0 = og * 160;
        float acc = 0.f;
        if (first) {
            const float* ar = Ws + k * CCH;
#pragma unroll 8
            for (int o = o0; o < o0 + 160; ++o)
                acc += ar[o] * Wa[o * CCH + c];
        } else {
#pragma unroll 8
            for (int o = o0; o < o0 + 160; ++o)
                acc += Ain[o * 9 + k] * Wa[o * CCH + c];
        }
        red[t] = acc;
        __syncthreads();
        if (t < 64) {
            float s = red[t] + red[64 + t] + red[128 + t] + red[192 + t];
            Aout[(ctile * 64 + t) * 9 + k] = s;
        }
    } else {
        int WB = (blk - 4090) * 4 + (t >> 6);
        if (WB >= 9) return;
        int k = WB;
        float acc = 0.f;
        if (first) {
            const float* ar = Ws + k * CCH;
#pragma unroll
            for (int s = 0; s < 10; ++s) acc += ar[s * 64 + lane] * ba[s * 64 + lane];
        } else {
#pragma unroll
            for (int s = 0; s < 10; ++s) acc += Ain[(s * 64 + lane) * 9 + k] * ba[s * 64 + lane];
        }
#pragma unroll
        for (int m = 32; m >= 1; m >>= 1) acc += __shfl_xor(acc, m);
        if (lane == 0) Bout[k] = acc + (first ? bs[k] : Bin[k]);
    }
}

// mlp1 K-split partials + fused sk (verbatim R0).
__global__ void postchain(const float* __restrict__ sf, const float* __restrict__ Pg0,
                          const float* __restrict__ Pgf, const float* __restrict__ W1,
                          float* __restrict__ Hp, const float* __restrict__ A4T,
                          const float* __restrict__ betaF, const float* __restrict__ Ws,
                          const float* __restrict__ bs, float* __restrict__ SKT,
                          float* __restrict__ SKS) {
    int blk = blockIdx.x, t = threadIdx.x;
    if (blk < 100) {
        int pair = blk / 2;
        int s = (blk % 2) * 2 + (t >> 7);
        int r = t & 127;
        int branch = pair / NBS, b = pair % NBS;
        const float* prow = (branch ? Pg0 : Pgf) + b * CCH;
        int c0 = s * 160;
        float acc = 0.f;
#pragma unroll 8
        for (int c = 0; c < 160; ++c)
            acc += prow[c0 + c] * W1[(c0 + c) * RDIM + r];
        Hp[(pair * 4 + s) * RDIM + r] = acc;
    } else {
        int sidx = (blk - 100) * 256 + t;
        if (sidx >= 45000) return;
        int s = sidx / 22500;
        int rem = sidx % 22500;
        int b = rem / 900;
        int r2 = rem % 900;          // flat f = k*100 + q
        int k = r2 / HWPIX, q = r2 % HWPIX;
        const float* x = sf + b * SF_B + q;
        const float* wsr = Ws + k * CCH;
        int c0 = s * 320;
        float acc0 = 0.f, acc1 = 0.f;
#pragma unroll 8
        for (int c = 0; c < 320; ++c) {
            float xc = x[(c0 + c) * HWPIX];
            acc0 += A4T[(c0 + c) * 9 + k] * xc;
            acc1 += wsr[c0 + c] * xc;
        }
        if (s == 0) { acc0 += betaF[k]; acc1 += bs[k]; }
        int p = r2 / 9, uv = r2 % 9;           // view coords of flat offset r2
        int dst = s * 22500 + b * 900 + uv * 100 + p;
        SKT[dst] = acc0;
        SKS[dst] = acc1;
    }
}

// ck for both branches per block: 225 blocks (b x 9 chunks of 640 j), 320 threads
// (verbatim R0 — proven shape; R9's 20-block fusion was a 497us occupancy disaster)
__global__ void mlp_phase2(const float* __restrict__ Hp, const float* __restrict__ b1,
                           const float* __restrict__ W2, const float* __restrict__ b2,
                           float* __restrict__ ckt, float* __restrict__ cks) {
    __shared__ float hs0[RDIM], hs1[RDIM];
    int b = blockIdx.x / 9, chunk = blockIdx.x % 9;
    int t = threadIdx.x;
    if (t < RDIM) {
        const float* hp = Hp + b * 4 * RDIM;
        hs0[t] = fmaxf(b1[t] + hp[t] + hp[RDIM + t] + hp[2 * RDIM + t] + hp[3 * RDIM + t], 0.f);
    } else if (t < 2 * RDIM) {
        int r = t - RDIM;
        const float* hp = Hp + (NBS + b) * 4 * RDIM;
        hs1[r] = fmaxf(b1[r] + hp[r] + hp[RDIM + r] + hp[2 * RDIM + r] + hp[3 * RDIM + r], 0.f);
    }
    __syncthreads();
    int jbase = chunk * 640;
    float a00 = b2[jbase + t], a01 = b2[jbase + t + 320];
    float a10 = a00, a11 = a01;
#pragma unroll 4
    for (int r = 0; r < RDIM; ++r) {
        const float* wrow = W2 + r * CKK + jbase;
        float w0 = wrow[t], w1 = wrow[t + 320];
        float h0 = hs0[r], h1 = hs1[r];
        a00 += h0 * w0; a01 += h0 * w1;
        a10 += h1 * w0; a11 += h1 * w1;
    }
    float* c0 = ckt + b * CKK + jbase;
    float* c1 = cks + b * CKK + jbase;
    c0[t] = a00; c0[t + 320] = a01;
    c1[t] = a10; c1[t + 320] = a11;
}

// taskT + sksT combine (verbatim R0).
__global__ void task_assemble(const float* __restrict__ ckt, const float* __restrict__ SKT,
                              const float* __restrict__ SKS, float* __restrict__ taskT,
                              float* __restrict__ sksT) {
    int blk = blockIdx.x, t = threadIdx.x;
    if (blk < 2250) {
        int idx = blk * 256 + t;          // uv*64000 + c*100 + p
        int uv = idx / 64000;
        int rem = idx % 64000;
        int c = rem / 100, p = rem % 100;
        float acc = 0.f;
#pragma unroll
        for (int b = 0; b < NBS; ++b)
            acc += ckt[b * CKK + c * 9 + uv] *
                   (SKT[b * 900 + uv * 100 + p] + SKT[22500 + b * 900 + uv * 100 + p]);
        taskT[idx] = acc * 0.04f;
    } else {
        int cidx = (blk - 2250) * 256 + t;
        if (cidx >= 22500) return;
        int uv = cidx / 2500;
        int r = cidx % 2500;              // b*100+p
        int src = (r / 100) * 900 + uv * 100 + (r % 100);
        sksT[cidx] = SKS[src] + SKS[22500 + src];
    }
}

// Involutions, image-loop restructure (verified in R9): block owns 256 (c,p)
// pairs x 25 images; taskT read once into registers (was ~230 MB of repeated
// L2 reads). g=0 blocks all-support, g=1..3 all-query -> block-uniform branch.
__global__ __launch_bounds__(256) void involutions(
        const float* __restrict__ sf, const float* __restrict__ qf,
        const float* __restrict__ taskT, const float* __restrict__ cks,
        const float* __restrict__ sksT, float* __restrict__ out) {
    int blk = blockIdx.x, t = threadIdx.x;
    int g = blk / 250;                         // image group: 25 images each
    int cpidx = (blk % 250) * 256 + t;         // 0..63999 exactly
    int c = cpidx / 100, p = cpidx % 100;
    int i = p / 10, j = p % 10;

    float tk[9];
#pragma unroll
    for (int uv = 0; uv < 9; ++uv) tk[uv] = taskT[uv * 64000 + cpidx];

    int im0 = g * 25;
#pragma unroll 1
    for (int im = im0; im < im0 + 25; ++im) {
        bool support = im < NBS;               // uniform within block
        const float* x = (support ? sf + im * SF_B : qf + (im - NBS) * SF_B) + c * 100;
        float w[9];
        if (support) {
#pragma unroll
            for (int uv = 0; uv < 9; ++uv)
                w[uv] = tk[uv] * cks[im * CKK + c * 9 + uv] *
                        sksT[uv * 2500 + im * 100 + p];
        } else {
#pragma unroll
            for (int uv = 0; uv < 9; ++uv) w[uv] = tk[uv];
        }
        float acc = 0.f;
#pragma unroll
        for (int u = 0; u < 3; ++u) {
            int ii = i + u - 1;
            float mrow = ((unsigned)ii < 10u) ? 1.f : 0.f;
            int ci = min(max(ii, 0), 9);
#pragma unroll
            for (int v = 0; v < 3; ++v) {
                int jj = j + v - 1;
                float m = ((unsigned)jj < 10u) ? mrow : 0.f;
                int cj = min(max(jj, 0), 9);
                float xv = x[ci * 10 + cj] * m;   // clamped addr, masked value
                acc += w[u * 3 + v] * xv;
            }
        }
        out[im * SF_B + cpidx] = acc;
    }
}

extern "C" void kernel_launch(void* const* d_in, const int* in_sizes, int n_in,
                              void* d_out, int out_size, void* d_ws, size_t ws_size,
                              hipStream_t stream) {
    const float* sf  = (const float*)d_in[0];
    const float* qf  = (const float*)d_in[1];
    const float* Wc[4] = {(const float*)d_in[2], (const float*)d_in[4],
                          (const float*)d_in[6], (const float*)d_in[8]};
    const float* bc[4] = {(const float*)d_in[3], (const float*)d_in[5],
                          (const float*)d_in[7], (const float*)d_in[9]};
    const float* W1 = (const float*)d_in[10];
    const float* b1 = (const float*)d_in[11];
    const float* W2 = (const float*)d_in[12];
    const float* b2 = (const float*)d_in[13];
    const float* Ws = (const float*)d_in[14];
    const float* bs = (const float*)d_in[15];
    float* out = (float*)d_out;
    float* ws = (float*)d_ws;

    float* Pg0 = ws + OFF_PG0;
    float* Pga = ws + OFF_PGA;
    float* Pgb = ws + OFF_PGB;
    float* ATa = ws + OFF_ATA;
    float* ATb = ws + OFF_ATB;
    float* Ba  = ws + OFF_BA;
    float* Bb  = ws + OFF_BB;
    float* Hp  = ws + OFF_HP;
    float* SKT = ws + OFF_SKT;
    float* SKS = ws + OFF_SKS;
    float* SKsT= ws + OFF_SKSCT;
    float* CKT = ws + OFF_CKT;
    float* CKS = ws + OFF_CKS;
    float* TKT = ws + OFF_TASKT;

    pool_kernel<<<250, 64, 0, stream>>>(sf, Pg0);

    chain_step<<<4093, 256, 0, stream>>>(Pg0, Wc[0], bc[0], Pga, nullptr, Wc[3], bc[3], nullptr,
                                         ATa, Ba, 1, Ws, bs);
    chain_step<<<4093, 256, 0, stream>>>(Pga, Wc[1], bc[1], Pgb, ATa, Wc[2], bc[2], Ba,
                                         ATb, Bb, 0, Ws, bs);
    chain_step<<<4093, 256, 0, stream>>>(Pgb, Wc[2], bc[2], Pga, ATb, Wc[1], bc[1], Bb,
                                         ATa, Ba, 0, Ws, bs);
    chain_step<<<4093, 256, 0, stream>>>(Pga, Wc[3], bc[3], Pgb, ATa, Wc[0], bc[0], Ba,
                                         ATb, Bb, 0, Ws, bs);
    // pooled_t = Pgb, A4^T = ATb, beta4 = Bb

    postchain<<<276, 256, 0, stream>>>(sf, Pg0, Pgb, W1, Hp, ATb, Bb, Ws, bs, SKT, SKS);
    mlp_phase2<<<225, 320, 0, stream>>>(Hp, b1, W2, b2, CKT, CKS);
    task_assemble<<<2338, 256, 0, stream>>>(CKT, SKT, SKS, TKT, SKsT);
    involutions<<<1000, 256, 0, stream>>>(sf, qf, TKT, CKS, SKsT, out);
}